// Round 14
// baseline (649.022 us; speedup 1.0000x reference)
//
#include <hip/hip_runtime.h>
#include <cstddef>
#include <cstdint>

#define L_SEQ 2048
#define D_MODEL 2048
#define NH 16
#define DH 128
#define M_ROWS 4096   // B * L

// ---------------------------------------------------------------------------
// bf16 helpers (storage type: ushort). f2bf uses the native __bf16 cast.
// ---------------------------------------------------------------------------
__device__ __forceinline__ ushort f2bf(float f) {
    union { __bf16 b; ushort u; } v; v.b = (__bf16)f; return v.u;
}
__device__ __forceinline__ float bf2f(ushort h) {
    union { uint32_t u; float f; } v; v.u = ((uint32_t)h) << 16; return v.f;
}
__device__ __forceinline__ float2 bf2f2(uint32_t u) {
    union { uint32_t u; float f; } lo, hi;
    lo.u = u << 16; hi.u = u & 0xffff0000u;
    return make_float2(lo.f, hi.f);
}

__device__ __forceinline__ void gld_lds16(const void* g, void* l) {
    __builtin_amdgcn_global_load_lds(
        (const __attribute__((address_space(1))) void*)g,
        (__attribute__((address_space(3))) void*)l, 16, 0, 0);
}

typedef __bf16  bf16x8 __attribute__((ext_vector_type(8)));
typedef float   f32x4  __attribute__((ext_vector_type(4)));

// ---------------------------------------------------------------------------
// fp32 -> bf16 elementwise (8 elems/thread)
// ---------------------------------------------------------------------------
__global__ __launch_bounds__(256) void cvt_bf16(
    const float* __restrict__ in, ushort* __restrict__ out)
{
    const int i = (blockIdx.x * 256 + threadIdx.x) * 8;
    const float4 a = *(const float4*)&in[i];
    const float4 b = *(const float4*)&in[i + 4];
    uint4 o;
    o.x = (uint)f2bf(a.x) | ((uint)f2bf(a.y) << 16);
    o.y = (uint)f2bf(a.z) | ((uint)f2bf(a.w) << 16);
    o.z = (uint)f2bf(b.x) | ((uint)f2bf(b.y) << 16);
    o.w = (uint)f2bf(b.z) | ((uint)f2bf(b.w) << 16);
    *(uint4*)&out[i] = o;
}

// ---------------------------------------------------------------------------
// W [K,N] fp32 -> Wt [N,K] bf16 (32x32 LDS tile transpose)
// ---------------------------------------------------------------------------
__global__ __launch_bounds__(256) void transpose_cvt(
    const float* __restrict__ W, ushort* __restrict__ Wt, int K, int N)
{
    __shared__ float tile[32][33];
    const int n0 = blockIdx.x * 32, k0 = blockIdx.y * 32;
    const int t = threadIdx.x;
    const int r = t >> 3;          // 0..31
    const int c4 = (t & 7) * 4;    // 0..28
    const float4 v = *(const float4*)&W[(size_t)(k0 + r) * N + n0 + c4];
    tile[r][c4 + 0] = v.x; tile[r][c4 + 1] = v.y;
    tile[r][c4 + 2] = v.z; tile[r][c4 + 3] = v.w;
    __syncthreads();
    ushort4 o;
    o.x = f2bf(tile[c4 + 0][r]);
    o.y = f2bf(tile[c4 + 1][r]);
    o.z = f2bf(tile[c4 + 2][r]);
    o.w = f2bf(tile[c4 + 3][r]);
    *(ushort4*)&Wt[(size_t)(n0 + r) * K + k0 + c4] = o;
}

// ---------------------------------------------------------------------------
// RoPE cos/sin table: Rtab[l*64 + d] = {cos, sin}(l * 10000^(-d/64))
// ---------------------------------------------------------------------------
__global__ __launch_bounds__(256) void rope_table(float2* __restrict__ tab)
{
    const int i = blockIdx.x * 256 + threadIdx.x;   // 131072
    const int d = i & 63, l = i >> 6;
    const float inv = exp2f(-(float)d * 0.20762050593045857f); // log2(1e4)/64
    const float ang = (float)l * inv;
    float s, c;
    sincosf(ang, &s, &c);
    tab[i] = make_float2(c, s);
}

// ---------------------------------------------------------------------------
// K RoPE in-place on bf16 via table. One thread per (row, head, d-pair).
// ---------------------------------------------------------------------------
__global__ __launch_bounds__(256) void rope_k(
    ushort* __restrict__ T, const float2* __restrict__ tab)
{
    const int idx = blockIdx.x * 256 + threadIdx.x;  // 4096*16*32
    const int d2   = (idx & 31) * 2;
    const int head = (idx >> 5) & 15;
    const int row  = idx >> 9;
    const int l    = row & (L_SEQ - 1);
    const size_t base = (size_t)row * 2048 + head * 128 + d2;
    const uint a = *(const uint*)&T[base];
    const uint b = *(const uint*)&T[base + 64];
    const float2 t0 = bf2f2(a);   // d2, d2+1 (lo half)
    const float2 t1 = bf2f2(b);   // d2+64, d2+65
    const float2 cs0 = tab[l * 64 + d2];
    const float2 cs1 = tab[l * 64 + d2 + 1];
    const float o0x = t0.x * cs0.x - t1.x * cs0.y;
    const float o0y = t0.y * cs1.x - t1.y * cs1.y;
    const float o1x = t1.x * cs0.x + t0.x * cs0.y;
    const float o1y = t1.y * cs1.x + t0.y * cs1.y;
    *(uint*)&T[base]      = (uint)f2bf(o0x) | ((uint)f2bf(o0y) << 16);
    *(uint*)&T[base + 64] = (uint)f2bf(o1x) | ((uint)f2bf(o1y) << 16);
}

// ---------------------------------------------------------------------------
// 256x256-tile bf16 MFMA GEMM, 8 waves (2Mx4N), BK=64, double-buffered LDS
// phase pipeline (R13). C[M,N] = A[M,K].Bt[N,K]^T.
// Per K-tile: 4 phases x {12 ds_read_b128 | stage 1 half-tile of K-tile t+1
// via global_load_lds | barrier | lgkmcnt(0) | 16 MFMA}; vmcnt(0) only at
// phase 3 (loads issued up to 3 phases earlier -> drain mostly free).
// LDS 128KB = 2 dbuf x (A 2x128x64 + B 2x128x64). Linear dest + involution
// swizzle (granule ^ (row&7)) on source and read side (R12-proven pattern).
// K-ascending accumulation -> bit-identical to the old 128x32-step kernel.
// MODE 0: f32 out ; MODE 1: bf16 out ; MODE 3: bf16 out into Vt layout.
// ---------------------------------------------------------------------------
template <int MODE>
__global__ __launch_bounds__(512, 2) void gemm256(
    const ushort* __restrict__ A, const ushort* __restrict__ Bt,
    void* __restrict__ Cv, int M, int N, int K)
{
    __shared__ __align__(16) ushort lds[65536];   // 131072 B
    const int t = threadIdx.x;
    const int lane = t & 63;
    const int w = t >> 6;
    const int wr = w >> 2, wc = w & 3;
    const int bm = blockIdx.y * 256;
    const int bn = blockIdx.x * 256;
    const int fr = lane & 15;
    const int quad = lane >> 4;

    // staging geometry: thread t covers granule (t&7)^(row&7) of row t>>3
    // (round 0) and row 64+(t>>3) (round 1; same ^(r&7) since +64 keeps r&7).
    const int sr0 = t >> 3;
    const int sg0 = (t & 7) ^ (sr0 & 7);

    const int nkt = K >> 6;   // K-tiles of 64

    f32x4 acc[8][4] = {};

    // prologue: stage K-tile 0 into dbuf 0 (A half0, A half1, B half0, B half1)
    #pragma unroll
    for (int q = 0; q < 4; ++q) {
        ushort* dst = &lds[(q < 2 ? q * 8192 : 16384 + (q - 2) * 8192)
                           + (size_t)t * 8];
        const ushort* src = (q < 2)
            ? A  + (size_t)(bm + q * 128 + sr0) * K + sg0 * 8
            : Bt + (size_t)(bn + (q - 2) * 128 + sr0) * K + sg0 * 8;
        gld_lds16(src, dst);
        gld_lds16(src + (size_t)64 * K, dst + 4096);
    }
    __syncthreads();   // drains vmcnt: tile 0 resident

    for (int kt = 0; kt < nkt; ++kt) {
        const int d = kt & 1;
        const ushort* Ah = &lds[d * 32768 + wr * 8192];
        const ushort* Bh = &lds[d * 32768 + 16384 + (wc >> 1) * 8192];
        const int brow0 = (wc & 1) * 64;
        const bool doStage = (kt + 1 < nkt);
        const int ktN = (kt + 1) * 64;

        #pragma unroll
        for (int q = 0; q < 4; ++q) {
            const int mq = q >> 1, nq = q & 1;
            // ---- ds-read this quadrant's fragments (current dbuf) ----
            bf16x8 af[4][2], bfr[2][2];
            #pragma unroll
            for (int i = 0; i < 4; ++i)
                #pragma unroll
                for (int ks = 0; ks < 2; ++ks) {
                    const int r = mq * 64 + i * 16 + fr;
                    const int slot = (quad + ks * 4) ^ (r & 7);
                    af[i][ks] = *(const bf16x8*)&Ah[r * 64 + slot * 8];
                }
            #pragma unroll
            for (int j = 0; j < 2; ++j)
                #pragma unroll
                for (int ks = 0; ks < 2; ++ks) {
                    const int rb = brow0 + nq * 32 + j * 16 + fr;
                    const int slot = (quad + ks * 4) ^ (rb & 7);
                    bfr[j][ks] = *(const bf16x8*)&Bh[rb * 64 + slot * 8];
                }
            // ---- stage half-tile q of K-tile kt+1 into dbuf d^1 ----
            if (doStage) {
                ushort* dst = &lds[(d ^ 1) * 32768
                    + (q < 2 ? q * 8192 : 16384 + (q - 2) * 8192)
                    + (size_t)t * 8];
                const ushort* src = (q < 2)
                    ? A  + (size_t)(bm + q * 128 + sr0) * K + ktN + sg0 * 8
                    : Bt + (size_t)(bn + (q - 2) * 128 + sr0) * K + ktN + sg0 * 8;
                gld_lds16(src, dst);
                gld_lds16(src + (size_t)64 * K, dst + 4096);
            }
            __builtin_amdgcn_s_barrier();
            asm volatile("s_waitcnt lgkmcnt(0)" ::: "memory");
            __builtin_amdgcn_sched_barrier(0);
            __builtin_amdgcn_s_setprio(1);
            #pragma unroll
            for (int i = 0; i < 4; ++i)
                #pragma unroll
                for (int j = 0; j < 2; ++j)
                    #pragma unroll
                    for (int ks = 0; ks < 2; ++ks)
                        acc[mq * 4 + i][nq * 2 + j] =
                            __builtin_amdgcn_mfma_f32_16x16x32_bf16(
                                af[i][ks], bfr[j][ks],
                                acc[mq * 4 + i][nq * 2 + j], 0, 0, 0);
            __builtin_amdgcn_s_setprio(0);
            if (q == 3)
                asm volatile("s_waitcnt vmcnt(0)" ::: "memory");
            __builtin_amdgcn_s_barrier();
            __builtin_amdgcn_sched_barrier(0);
        }
    }

    // ---- epilogue C-write ----
    const int crow = (lane >> 4) * 4;
    const int ccol = lane & 15;
    #pragma unroll
    for (int mf = 0; mf < 8; ++mf) {
        #pragma unroll
        for (int nf = 0; nf < 4; ++nf) {
            if (MODE == 3) {
                const size_t row = bm + wr * 128 + mf * 16 + crow;  // b*2048+l
                const size_t col = bn + wc * 64 + nf * 16 + ccol;   // h*128+d
                ushort4 o4;
                o4.x = f2bf(acc[mf][nf][0]); o4.y = f2bf(acc[mf][nf][1]);
                o4.z = f2bf(acc[mf][nf][2]); o4.w = f2bf(acc[mf][nf][3]);
                *(ushort4*)&((ushort*)Cv)[
                    ((row >> 11) * 16 + (col >> 7)) * (size_t)(128 * 2048)
                    + (col & 127) * 2048 + (row & 2047)] = o4;
            } else {
                #pragma unroll
                for (int reg = 0; reg < 4; ++reg) {
                    const size_t row = bm + wr * 128 + mf * 16 + crow + reg;
                    const size_t col = bn + wc * 64 + nf * 16 + ccol;
                    if (MODE == 1) {
                        ((ushort*)Cv)[row * N + col] = f2bf(acc[mf][nf][reg]);
                    } else {
                        ((float*)Cv)[row * N + col] = acc[mf][nf][reg];
                    }
                }
            }
        }
    }
}

// ---------------------------------------------------------------------------
// lam = sigmoid(x @ Wl + bl). hh in lane bits 0-3 keeps Wl reads coalesced
// (R10 lesson); 2-way split in bit 4, shfl_xor(16) reduce.
// ---------------------------------------------------------------------------
__global__ __launch_bounds__(256) void lam_kernel(
    const float* __restrict__ X, const float* __restrict__ Wl,
    const float* __restrict__ bl, float* __restrict__ Lam)
{
    const int idx  = blockIdx.x * 256 + threadIdx.x;   // 131072
    const int hh   = idx & 15;
    const int part = (idx >> 4) & 1;
    const int m    = idx >> 5;
    const float* xr = X + (size_t)m * D_MODEL + part * 1024;
    const float* wl = Wl + (size_t)(part * 1024) * NH;
    float acc = 0.0f;
    for (int d = 0; d < 1024; d += 4) {
        const float4 xv = *(const float4*)&xr[d];
        acc += xv.x * wl[(d + 0) * NH + hh];
        acc += xv.y * wl[(d + 1) * NH + hh];
        acc += xv.z * wl[(d + 2) * NH + hh];
        acc += xv.w * wl[(d + 3) * NH + hh];
    }
    acc += __shfl_xor(acc, 16);
    if (part == 0) {
        acc += bl[hh];
        Lam[(size_t)m * NH + hh] = 1.0f / (1.0f + expf(-acc));
    }
}

// ---------------------------------------------------------------------------
// MFMA differential causal flash attention, v6 (R12 verified: 184us,
// 3-region rotating LDS pipeline, gld_lds staging, involution swizzle).
// ---------------------------------------------------------------------------
__global__ __launch_bounds__(256, 2) void attn_mfma(
    const ushort* __restrict__ Qb, const ushort* __restrict__ Kb,
    const ushort* __restrict__ Vtg, const float* __restrict__ Lam,
    const float2* __restrict__ Rtab, ushort* __restrict__ OutB)
{
    __shared__ __align__(16) ushort lds[33792];   // 67584 B
    ushort* P_sh = lds + 24576;     // 4 waves x [32][72]

    const int h  = blockIdx.y;
    const int b  = blockIdx.z;
    const int pt = blockIdx.x;
    const int t  = threadIdx.x;
    const int w = t >> 6, lane = t & 63;
    const int colL = lane & 15, quad = lane >> 4;
    const int p = w >> 1, slot = w & 1;
    ushort* Pw = P_sh + w * (32 * 72);

    const ushort* Kgbase = Kb  + (size_t)(b * 2048) * 2048 + h * 128;
    const ushort* Vgbase = Vtg + (size_t)((b * 16 + h) * 128) * 2048;
    const float scale2 = 0.12751744f;   // log2(e)/sqrt(128)

    auto stageK = [&](ushort* dst, int kt0) {
        #pragma unroll
        for (int j = 0; j < 4; ++j) {
            const int idx = j * 256 + t;
            const int kr = idx >> 4;
            const int kg = t & 15;
            gld_lds16(Kgbase + (size_t)(kt0 + kr) * 2048 + ((kg ^ (kr & 15)) << 3),
                      dst + (size_t)idx * 8);
        }
    };
    auto stageV = [&](ushort* dst, int kt0) {
        #pragma unroll
        for (int j = 0; j < 4; ++j) {
            const int idx = j * 256 + t;
            const int vr = idx >> 3;
            const int vg = t & 7;
            gld_lds16(Vgbase + (size_t)vr * 2048 + kt0 + ((vg ^ (vr & 7)) << 3),
                      dst + (size_t)idx * 8);
        }
    };

    for (int ph = 0; ph < 2; ++ph) {
        const int qt  = ph ? pt : 31 - pt;
        const int q0  = qt * 64;
        const int r0w = q0 + slot * 32;

        // ---- load Q frags + fused RoPE ----
        bf16x8 qf[2][4];
        #pragma unroll
        for (int g = 0; g < 2; ++g) {
            const int l = r0w + g * 16 + colL;
            const ushort* Qr = Qb + (size_t)(b * 2048 + l) * 4096
                             + (2 * h + p) * 128 + quad * 8;
            ushort raw[4][8];
            #pragma unroll
            for (int c = 0; c < 4; ++c)
                *(uint4*)raw[c] = *(const uint4*)&Qr[c * 32];
            const float2* tb = Rtab + l * 64 + quad * 8;
            ushort o[4][8];
            #pragma unroll
            for (int c = 0; c < 2; ++c)
                #pragma unroll
                for (int j = 0; j < 8; ++j) {
                    const float2 cs = tb[c * 32 + j];
                    const float a  = bf2f(raw[c][j]);
                    const float bb = bf2f(raw[c + 2][j]);
                    o[c][j]     = f2bf(a * cs.x - bb * cs.y);
                    o[c + 2][j] = f2bf(bb * cs.x + a * cs.y);
                }
            #pragma unroll
            for (int c = 0; c < 4; ++c)
                qf[g][c] = *(const bf16x8*)o[c];
        }

        f32x4 ctx[2][8] = {};
        float m2[2][4] = {{-1e30f,-1e30f,-1e30f,-1e30f},
                          {-1e30f,-1e30f,-1e30f,-1e30f}};
        float li[2][4] = {};

        ushort* Kc = lds;
        ushort* Vc = lds + 8192;
        ushort* Fr = lds + 16384;

        stageK(Kc, 0);
        stageV(Vc, 0);
        __syncthreads();

        for (int kt = 0; kt <= qt; ++kt) {
            const int kt0 = kt * 64;

            // ---- QK^T ----
            f32x4 sc2[2][4] = {};
            __builtin_amdgcn_s_setprio(1);
            #pragma unroll
            for (int c = 0; c < 4; ++c)
                #pragma unroll
                for (int nt = 0; nt < 4; ++nt) {
                    const int krow = nt * 16 + colL;
                    const bf16x8 kf = *(const bf16x8*)
                        &Kc[krow * 128 + (((c * 4 + quad) ^ (krow & 15)) << 3)];
                    sc2[0][nt] = __builtin_amdgcn_mfma_f32_16x16x32_bf16(
                        qf[0][c], kf, sc2[0][nt], 0, 0, 0);
                    sc2[1][nt] = __builtin_amdgcn_mfma_f32_16x16x32_bf16(
                        qf[1][c], kf, sc2[1][nt], 0, 0, 0);
                }
            __builtin_amdgcn_s_setprio(0);

            __syncthreads();   // all waves done reading Kc
            if (kt < qt) {
                stageK(Fr, kt0 + 64);
                stageV(Kc, kt0 + 64);
            }

            const bool dmask = (kt == qt);
            // ---- online softmax (exp2 domain, defer-max T13) ----
            #pragma unroll
            for (int g = 0; g < 2; ++g)
                #pragma unroll
                for (int reg = 0; reg < 4; ++reg) {
                    const int row = r0w + g * 16 + quad * 4 + reg;
                    float s[4];
                    #pragma unroll
                    for (int nt = 0; nt < 4; ++nt) {
                        float v = sc2[g][nt][reg] * scale2;
                        if (dmask && (kt0 + nt * 16 + colL > row)) v = -1e9f;
                        s[nt] = v;
                    }
                    float mx = fmaxf(fmaxf(s[0], s[1]), fmaxf(s[2], s[3]));
                    #pragma unroll
                    for (int off = 8; off >= 1; off >>= 1)
                        mx = fmaxf(mx, __shfl_xor(mx, off));
                    if (__any(mx > m2[g][reg] + 11.0f)) {
                        const float mnew  = fmaxf(m2[g][reg], mx);
                        const float alpha = exp2f(m2[g][reg] - mnew);
                        li[g][reg] *= alpha;
                        m2[g][reg] = mnew;
                        #pragma unroll
                        for (int nt2 = 0; nt2 < 8; ++nt2)
                            ctx[g][nt2][reg] *= alpha;
                    }
                    float rs = 0.f;
                    #pragma unroll
                    for (int nt = 0; nt < 4; ++nt) {
                        const float pv = exp2f(s[nt] - m2[g][reg]);
                        s[nt] = pv;
                        rs += pv;
                    }
                    #pragma unroll
                    for (int off = 8; off >= 1; off >>= 1)
                        rs += __shfl_xor(rs, off);
                    li[g][reg] += rs;
                    #pragma unroll
                    for (int nt = 0; nt < 4; ++nt)
                        Pw[(g * 16 + quad * 4 + reg) * 72 + nt * 16 + colL]
                            = f2bf(s[nt]);
                }

            // ---- PV ----
            __builtin_amdgcn_s_setprio(1);
            #pragma unroll
            for (int c2 = 0; c2 < 2; ++c2) {
                const bf16x8 pf0 = *(const bf16x8*)
                    &Pw[colL * 72 + c2 * 32 + quad * 8];
                const bf16x8 pf1 = *(const bf16x8*)
                    &Pw[(16 + colL) * 72 + c2 * 32 + quad * 8];
                #pragma unroll
                for (int nt2 = 0; nt2 < 8; ++nt2) {
                    const int vrow = nt2 * 16 + colL;
                    const bf16x8 vf = *(const bf16x8*)
                        &Vc[vrow * 64 + (((c2 * 4 + quad) ^ (vrow & 7)) << 3)];
                    ctx[0][nt2] = __builtin_amdgcn_mfma_f32_16x16x32_bf16(
                        pf0, vf, ctx[0][nt2], 0, 0, 0);
                    ctx[1][nt2] = __builtin_amdgcn_mfma_f32_16x16x32_bf16(
                        pf1, vf, ctx[1][nt2], 0, 0, 0);
                }
            }
            __builtin_amdgcn_s_setprio(0);

            __syncthreads();
            ushort* tmp = Fr; Fr = Vc; Vc = Kc; Kc = tmp;
        }

        float invl[2][4];
        #pragma unroll
        for (int g = 0; g < 2; ++g)
            #pragma unroll
            for (int reg = 0; reg < 4; ++reg)
                invl[g][reg] = 1.0f / li[g][reg];

        // ---- differential combine through LDS ----
        float* comb = (float*)lds;   // [64][130] f32
        __syncthreads();
        if (p == 1) {
            #pragma unroll
            for (int g = 0; g < 2; ++g)
                #pragma unroll
                for (int nt2 = 0; nt2 < 8; ++nt2)
                    #pragma unroll
                    for (int reg = 0; reg < 4; ++reg)
                        comb[(slot * 32 + g * 16 + quad * 4 + reg) * 130
                             + nt2 * 16 + colL] = ctx[g][nt2][reg] * invl[g][reg];
        }
        __syncthreads();
        if (p == 0) {
            #pragma unroll
            for (int g = 0; g < 2; ++g)
                #pragma unroll
                for (int reg = 0; reg < 4; ++reg) {
                    const int row = r0w + g * 16 + quad * 4 + reg;
                    const float lamv = Lam[(size_t)(b * 2048 + row) * 16 + h];
                    ushort* orow = OutB + (size_t)(b * 2048 + row) * 2048 + h * 128;
                    #pragma unroll
                    for (int nt2 = 0; nt2 < 8; ++nt2) {
                        const float c1 = comb[(slot * 32 + g * 16 + quad * 4 + reg) * 130
                                              + nt2 * 16 + colL];
                        const float o = ctx[g][nt2][reg] * invl[g][reg] - lamv * c1;
                        orow[nt2 * 16 + colL] = f2bf(o);
                    }
                }
        }
        __syncthreads();
    }
}

// ---------------------------------------------------------------------------
extern "C" void kernel_launch(void* const* d_in, const int* in_sizes, int n_in,
                              void* d_out, int out_size, void* d_ws, size_t ws_size,
                              hipStream_t stream)
{
    const float* x  = (const float*)d_in[0];
    const float* Wq = (const float*)d_in[1];
    const float* Wk = (const float*)d_in[2];
    const float* Wv = (const float*)d_in[3];
    const float* Wl = (const float*)d_in[4];
    const float* bl = (const float*)d_in[5];
    const float* Wo = (const float*)d_in[6];
    float* out = (float*)d_out;
    (void)ws_size; (void)in_sizes; (void)n_in; (void)out_size;

    ushort* ws   = (ushort*)d_ws;
    ushort* xb   = ws;                       // 4096x2048
    ushort* Qb16 = xb   + (size_t)8388608;   // 4096x4096
    ushort* Kb16 = Qb16 + (size_t)16777216;  // 4096x2048
    ushort* Vtg  = Kb16 + (size_t)8388608;   // 2x16x128x2048 (V^T)
    ushort* Wqt  = Vtg  + (size_t)8388608;   // 4096x2048 (Wq^T)
    ushort* Wkt  = Wqt  + (size_t)8388608;   // 2048x2048
    ushort* Wvt  = Wkt  + (size_t)4194304;   // 2048x2048
    ushort* Wot  = Wvt  + (size_t)4194304;   // 2048x2048
    ushort* OutB = Wot  + (size_t)4194304;   // 4096x2048
    float*  LamB = (float*)(OutB + (size_t)8388608);  // 4096x16
    float2* Rtab = (float2*)(LamB + (size_t)65536);   // 2048x64

    // dtype conversions + tables
    cvt_bf16<<<4096, 256, 0, stream>>>(x, xb);
    transpose_cvt<<<dim3(128, 64), 256, 0, stream>>>(Wq, Wqt, 2048, 4096);
    transpose_cvt<<<dim3(64, 64), 256, 0, stream>>>(Wk, Wkt, 2048, 2048);
    transpose_cvt<<<dim3(64, 64), 256, 0, stream>>>(Wv, Wvt, 2048, 2048);
    transpose_cvt<<<dim3(64, 64), 256, 0, stream>>>(Wo, Wot, 2048, 2048);
    lam_kernel<<<512, 256, 0, stream>>>(x, Wl, bl, LamB);
    rope_table<<<512, 256, 0, stream>>>(Rtab);

    // projections (256^2-tile pipelined bf16 MFMA); V written transposed
    gemm256<1><<<dim3(16, 16), 512, 0, stream>>>(xb, Wqt, Qb16, M_ROWS, 4096, D_MODEL);
    gemm256<1><<<dim3(8, 16), 512, 0, stream>>>(xb, Wkt, Kb16, M_ROWS, D_MODEL, D_MODEL);
    gemm256<3><<<dim3(8, 16), 512, 0, stream>>>(xb, Wvt, Vtg, M_ROWS, D_MODEL, D_MODEL);

    // RoPE on K (Q RoPE fused in attention)
    rope_k<<<8192, 256, 0, stream>>>(Kb16, Rtab);

    // MFMA differential causal flash attention -> OutB (bf16)
    attn_mfma<<<dim3(16, NH, 2), 256, 0, stream>>>(Qb16, Kb16, Vtg, LamB, Rtab, OutB);

    // final projection (fp32 out)
    gemm256<0><<<dim3(8, 16), 512, 0, stream>>>(OutB, Wot, out, M_ROWS, D_MODEL, D_MODEL);
}

// Round 15
// 574.150 us; speedup vs baseline: 1.1304x; 1.1304x over previous
//
#include <hip/hip_runtime.h>
#include <cstddef>
#include <cstdint>

#define L_SEQ 2048
#define D_MODEL 2048
#define NH 16
#define DH 128
#define M_ROWS 4096   // B * L

// ---------------------------------------------------------------------------
// bf16 helpers (storage type: ushort). f2bf uses the native __bf16 cast.
// ---------------------------------------------------------------------------
__device__ __forceinline__ ushort f2bf(float f) {
    union { __bf16 b; ushort u; } v; v.b = (__bf16)f; return v.u;
}
__device__ __forceinline__ float bf2f(ushort h) {
    union { uint32_t u; float f; } v; v.u = ((uint32_t)h) << 16; return v.f;
}
__device__ __forceinline__ float2 bf2f2(uint32_t u) {
    union { uint32_t u; float f; } lo, hi;
    lo.u = u << 16; hi.u = u & 0xffff0000u;
    return make_float2(lo.f, hi.f);
}

__device__ __forceinline__ void gld_lds16(const void* g, void* l) {
    __builtin_amdgcn_global_load_lds(
        (const __attribute__((address_space(1))) void*)g,
        (__attribute__((address_space(3))) void*)l, 16, 0, 0);
}

typedef __bf16  bf16x8 __attribute__((ext_vector_type(8)));
typedef float   f32x4  __attribute__((ext_vector_type(4)));

// ---------------------------------------------------------------------------
// fp32 -> bf16 elementwise (8 elems/thread)
// ---------------------------------------------------------------------------
__global__ __launch_bounds__(256) void cvt_bf16(
    const float* __restrict__ in, ushort* __restrict__ out)
{
    const int i = (blockIdx.x * 256 + threadIdx.x) * 8;
    const float4 a = *(const float4*)&in[i];
    const float4 b = *(const float4*)&in[i + 4];
    uint4 o;
    o.x = (uint)f2bf(a.x) | ((uint)f2bf(a.y) << 16);
    o.y = (uint)f2bf(a.z) | ((uint)f2bf(a.w) << 16);
    o.z = (uint)f2bf(b.x) | ((uint)f2bf(b.y) << 16);
    o.w = (uint)f2bf(b.z) | ((uint)f2bf(b.w) << 16);
    *(uint4*)&out[i] = o;
}

// ---------------------------------------------------------------------------
// W [K,N] fp32 -> Wt [N,K] bf16 (32x32 LDS tile transpose)
// ---------------------------------------------------------------------------
__global__ __launch_bounds__(256) void transpose_cvt(
    const float* __restrict__ W, ushort* __restrict__ Wt, int K, int N)
{
    __shared__ float tile[32][33];
    const int n0 = blockIdx.x * 32, k0 = blockIdx.y * 32;
    const int t = threadIdx.x;
    const int r = t >> 3;          // 0..31
    const int c4 = (t & 7) * 4;    // 0..28
    const float4 v = *(const float4*)&W[(size_t)(k0 + r) * N + n0 + c4];
    tile[r][c4 + 0] = v.x; tile[r][c4 + 1] = v.y;
    tile[r][c4 + 2] = v.z; tile[r][c4 + 3] = v.w;
    __syncthreads();
    ushort4 o;
    o.x = f2bf(tile[c4 + 0][r]);
    o.y = f2bf(tile[c4 + 1][r]);
    o.z = f2bf(tile[c4 + 2][r]);
    o.w = f2bf(tile[c4 + 3][r]);
    *(ushort4*)&Wt[(size_t)(n0 + r) * K + k0 + c4] = o;
}

// ---------------------------------------------------------------------------
// RoPE cos/sin table: Rtab[l*64 + d] = {cos, sin}(l * 10000^(-d/64))
// ---------------------------------------------------------------------------
__global__ __launch_bounds__(256) void rope_table(float2* __restrict__ tab)
{
    const int i = blockIdx.x * 256 + threadIdx.x;   // 131072
    const int d = i & 63, l = i >> 6;
    const float inv = exp2f(-(float)d * 0.20762050593045857f); // log2(1e4)/64
    const float ang = (float)l * inv;
    float s, c;
    sincosf(ang, &s, &c);
    tab[i] = make_float2(c, s);
}

// ---------------------------------------------------------------------------
// K RoPE in-place on bf16 via table. One thread per (row, head, d-pair).
// ---------------------------------------------------------------------------
__global__ __launch_bounds__(256) void rope_k(
    ushort* __restrict__ T, const float2* __restrict__ tab)
{
    const int idx = blockIdx.x * 256 + threadIdx.x;  // 4096*16*32
    const int d2   = (idx & 31) * 2;
    const int head = (idx >> 5) & 15;
    const int row  = idx >> 9;
    const int l    = row & (L_SEQ - 1);
    const size_t base = (size_t)row * 2048 + head * 128 + d2;
    const uint a = *(const uint*)&T[base];
    const uint b = *(const uint*)&T[base + 64];
    const float2 t0 = bf2f2(a);   // d2, d2+1 (lo half)
    const float2 t1 = bf2f2(b);   // d2+64, d2+65
    const float2 cs0 = tab[l * 64 + d2];
    const float2 cs1 = tab[l * 64 + d2 + 1];
    const float o0x = t0.x * cs0.x - t1.x * cs0.y;
    const float o0y = t0.y * cs1.x - t1.y * cs1.y;
    const float o1x = t1.x * cs0.x + t0.x * cs0.y;
    const float o1y = t1.y * cs1.x + t0.y * cs1.y;
    *(uint*)&T[base]      = (uint)f2bf(o0x) | ((uint)f2bf(o0y) << 16);
    *(uint*)&T[base + 64] = (uint)f2bf(o1x) | ((uint)f2bf(o1y) << 16);
}

// ---------------------------------------------------------------------------
// Tiled bf16 MFMA GEMM, 8 waves (2Mx4N), BN=256, BK=64, BM = MT*32
// (MT = per-wave m-frags). Double-buffered LDS phase pipeline (R13/R15).
// C[M,N] = A[M,K].Bt[N,K]^T.
// R15: MT=4 variant (128x256 tile) for N=2048 GEMMs -> grid 256 blocks
// (R14 used 256x256 -> 128 blocks = half machine idle). Qproj keeps MT=8.
// Per K-tile: 4 phases x {ds_read frags | stage chunk q of K-tile t+1 via
// global_load_lds | barrier | lgkmcnt(0) | MFMA}; vmcnt(0) only at phase 3.
// Linear LDS dest + involution swizzle (granule ^ (row&7)) both sides.
// K-ascending accumulation -> bit-identical across variants.
// MODE 0: f32 out ; MODE 1: bf16 out ; MODE 3: bf16 out into Vt layout.
// ---------------------------------------------------------------------------
template <int MODE, int MT>
__global__ __launch_bounds__(512, 2) void gemm_t(
    const ushort* __restrict__ A, const ushort* __restrict__ Bt,
    void* __restrict__ Cv, int M, int N, int K)
{
    constexpr int BM   = MT * 32;            // 128 or 256
    constexpr int ACH  = BM / 128;           // A 128-row chunks (1 or 2)
    constexpr int NCH  = ACH + 2;            // total staging chunks
    constexpr int DST  = BM * 64 + 16384;    // ushorts per dbuf
    __shared__ __align__(16) ushort lds[2 * DST];

    const int t = threadIdx.x;
    const int lane = t & 63;
    const int w = t >> 6;
    const int wr = w >> 2, wc = w & 3;       // 2M x 4N waves
    const int bm = blockIdx.y * BM;
    const int bn = blockIdx.x * 256;
    const int fr = lane & 15;
    const int quad = lane >> 4;

    // staging geometry: thread t covers granule (t&7)^(row&7) of rows
    // t>>3 and 64+(t>>3) within a 128-row chunk (+64 preserves row&7).
    const int sr0 = t >> 3;
    const int sg0 = (t & 7) ^ (sr0 & 7);

    const int nkt = K >> 6;   // K-tiles of 64

    f32x4 acc[MT][4] = {};

    // prologue: stage K-tile 0 into dbuf 0
    #pragma unroll
    for (int q = 0; q < NCH; ++q) {
        ushort* dst = &lds[(q < ACH ? q * 8192 : BM * 64 + (q - ACH) * 8192)
                           + (size_t)t * 8];
        const ushort* src = (q < ACH)
            ? A  + (size_t)(bm + q * 128 + sr0) * K + sg0 * 8
            : Bt + (size_t)(bn + (q - ACH) * 128 + sr0) * K + sg0 * 8;
        gld_lds16(src, dst);
        gld_lds16(src + (size_t)64 * K, dst + 4096);
    }
    __syncthreads();   // drains vmcnt: tile 0 resident

    for (int kt = 0; kt < nkt; ++kt) {
        const int d = kt & 1;
        const ushort* Ah = &lds[d * DST + wr * (BM / 2) * 64];
        const ushort* Bh = &lds[d * DST + BM * 64 + (wc >> 1) * 8192];
        const int brow0 = (wc & 1) * 64;
        const bool doStage = (kt + 1 < nkt);
        const int ktN = (kt + 1) * 64;

        #pragma unroll
        for (int q = 0; q < 4; ++q) {
            const int mq = q >> 1, nq = q & 1;
            // ---- ds-read this quadrant's fragments (current dbuf) ----
            bf16x8 af[MT / 2 > 2 ? MT / 2 : 2][2], bfr[2][2];
            #pragma unroll
            for (int i = 0; i < MT / 2; ++i)
                #pragma unroll
                for (int ks = 0; ks < 2; ++ks) {
                    const int r = mq * (BM / 4) + i * 16 + fr;
                    const int slot = (quad + ks * 4) ^ (r & 7);
                    af[i][ks] = *(const bf16x8*)&Ah[r * 64 + slot * 8];
                }
            #pragma unroll
            for (int j = 0; j < 2; ++j)
                #pragma unroll
                for (int ks = 0; ks < 2; ++ks) {
                    const int rb = brow0 + nq * 32 + j * 16 + fr;
                    const int slot = (quad + ks * 4) ^ (rb & 7);
                    bfr[j][ks] = *(const bf16x8*)&Bh[rb * 64 + slot * 8];
                }
            // ---- stage chunk q of K-tile kt+1 into dbuf d^1 ----
            if (doStage && q < NCH) {
                ushort* dst = &lds[(d ^ 1) * DST
                    + (q < ACH ? q * 8192 : BM * 64 + (q - ACH) * 8192)
                    + (size_t)t * 8];
                const ushort* src = (q < ACH)
                    ? A  + (size_t)(bm + q * 128 + sr0) * K + ktN + sg0 * 8
                    : Bt + (size_t)(bn + (q - ACH) * 128 + sr0) * K + ktN + sg0 * 8;
                gld_lds16(src, dst);
                gld_lds16(src + (size_t)64 * K, dst + 4096);
            }
            __builtin_amdgcn_s_barrier();
            asm volatile("s_waitcnt lgkmcnt(0)" ::: "memory");
            __builtin_amdgcn_sched_barrier(0);
            __builtin_amdgcn_s_setprio(1);
            #pragma unroll
            for (int i = 0; i < MT / 2; ++i)
                #pragma unroll
                for (int j = 0; j < 2; ++j)
                    #pragma unroll
                    for (int ks = 0; ks < 2; ++ks)
                        acc[mq * (MT / 2) + i][nq * 2 + j] =
                            __builtin_amdgcn_mfma_f32_16x16x32_bf16(
                                af[i][ks], bfr[j][ks],
                                acc[mq * (MT / 2) + i][nq * 2 + j], 0, 0, 0);
            __builtin_amdgcn_s_setprio(0);
            if (q == 3)
                asm volatile("s_waitcnt vmcnt(0)" ::: "memory");
            __builtin_amdgcn_s_barrier();
            __builtin_amdgcn_sched_barrier(0);
        }
    }

    // ---- epilogue C-write ----
    const int crow = (lane >> 4) * 4;
    const int ccol = lane & 15;
    #pragma unroll
    for (int mf = 0; mf < MT; ++mf) {
        #pragma unroll
        for (int nf = 0; nf < 4; ++nf) {
            if (MODE == 3) {
                const size_t row = bm + wr * (BM / 2) + mf * 16 + crow;
                const size_t col = bn + wc * 64 + nf * 16 + ccol;
                ushort4 o4;
                o4.x = f2bf(acc[mf][nf][0]); o4.y = f2bf(acc[mf][nf][1]);
                o4.z = f2bf(acc[mf][nf][2]); o4.w = f2bf(acc[mf][nf][3]);
                *(ushort4*)&((ushort*)Cv)[
                    ((row >> 11) * 16 + (col >> 7)) * (size_t)(128 * 2048)
                    + (col & 127) * 2048 + (row & 2047)] = o4;
            } else {
                #pragma unroll
                for (int reg = 0; reg < 4; ++reg) {
                    const size_t row = bm + wr * (BM / 2) + mf * 16 + crow + reg;
                    const size_t col = bn + wc * 64 + nf * 16 + ccol;
                    if (MODE == 1) {
                        ((ushort*)Cv)[row * N + col] = f2bf(acc[mf][nf][reg]);
                    } else {
                        ((float*)Cv)[row * N + col] = acc[mf][nf][reg];
                    }
                }
            }
        }
    }
}

// ---------------------------------------------------------------------------
// lam = sigmoid(x @ Wl + bl). hh in lane bits 0-3 keeps Wl reads coalesced
// (R10 lesson); 2-way split in bit 4, shfl_xor(16) reduce.
// ---------------------------------------------------------------------------
__global__ __launch_bounds__(256) void lam_kernel(
    const float* __restrict__ X, const float* __restrict__ Wl,
    const float* __restrict__ bl, float* __restrict__ Lam)
{
    const int idx  = blockIdx.x * 256 + threadIdx.x;   // 131072
    const int hh   = idx & 15;
    const int part = (idx >> 4) & 1;
    const int m    = idx >> 5;
    const float* xr = X + (size_t)m * D_MODEL + part * 1024;
    const float* wl = Wl + (size_t)(part * 1024) * NH;
    float acc = 0.0f;
    for (int d = 0; d < 1024; d += 4) {
        const float4 xv = *(const float4*)&xr[d];
        acc += xv.x * wl[(d + 0) * NH + hh];
        acc += xv.y * wl[(d + 1) * NH + hh];
        acc += xv.z * wl[(d + 2) * NH + hh];
        acc += xv.w * wl[(d + 3) * NH + hh];
    }
    acc += __shfl_xor(acc, 16);
    if (part == 0) {
        acc += bl[hh];
        Lam[(size_t)m * NH + hh] = 1.0f / (1.0f + expf(-acc));
    }
}

// ---------------------------------------------------------------------------
// MFMA differential causal flash attention, v6 (R12 verified: 184us,
// 3-region rotating LDS pipeline, gld_lds staging, involution swizzle).
// ---------------------------------------------------------------------------
__global__ __launch_bounds__(256, 2) void attn_mfma(
    const ushort* __restrict__ Qb, const ushort* __restrict__ Kb,
    const ushort* __restrict__ Vtg, const float* __restrict__ Lam,
    const float2* __restrict__ Rtab, ushort* __restrict__ OutB)
{
    __shared__ __align__(16) ushort lds[33792];   // 67584 B
    ushort* P_sh = lds + 24576;     // 4 waves x [32][72]

    const int h  = blockIdx.y;
    const int b  = blockIdx.z;
    const int pt = blockIdx.x;
    const int t  = threadIdx.x;
    const int w = t >> 6, lane = t & 63;
    const int colL = lane & 15, quad = lane >> 4;
    const int p = w >> 1, slot = w & 1;
    ushort* Pw = P_sh + w * (32 * 72);

    const ushort* Kgbase = Kb  + (size_t)(b * 2048) * 2048 + h * 128;
    const ushort* Vgbase = Vtg + (size_t)((b * 16 + h) * 128) * 2048;
    const float scale2 = 0.12751744f;   // log2(e)/sqrt(128)

    auto stageK = [&](ushort* dst, int kt0) {
        #pragma unroll
        for (int j = 0; j < 4; ++j) {
            const int idx = j * 256 + t;
            const int kr = idx >> 4;
            const int kg = t & 15;
            gld_lds16(Kgbase + (size_t)(kt0 + kr) * 2048 + ((kg ^ (kr & 15)) << 3),
                      dst + (size_t)idx * 8);
        }
    };
    auto stageV = [&](ushort* dst, int kt0) {
        #pragma unroll
        for (int j = 0; j < 4; ++j) {
            const int idx = j * 256 + t;
            const int vr = idx >> 3;
            const int vg = t & 7;
            gld_lds16(Vgbase + (size_t)vr * 2048 + kt0 + ((vg ^ (vr & 7)) << 3),
                      dst + (size_t)idx * 8);
        }
    };

    for (int ph = 0; ph < 2; ++ph) {
        const int qt  = ph ? pt : 31 - pt;
        const int q0  = qt * 64;
        const int r0w = q0 + slot * 32;

        // ---- load Q frags + fused RoPE ----
        bf16x8 qf[2][4];
        #pragma unroll
        for (int g = 0; g < 2; ++g) {
            const int l = r0w + g * 16 + colL;
            const ushort* Qr = Qb + (size_t)(b * 2048 + l) * 4096
                             + (2 * h + p) * 128 + quad * 8;
            ushort raw[4][8];
            #pragma unroll
            for (int c = 0; c < 4; ++c)
                *(uint4*)raw[c] = *(const uint4*)&Qr[c * 32];
            const float2* tb = Rtab + l * 64 + quad * 8;
            ushort o[4][8];
            #pragma unroll
            for (int c = 0; c < 2; ++c)
                #pragma unroll
                for (int j = 0; j < 8; ++j) {
                    const float2 cs = tb[c * 32 + j];
                    const float a  = bf2f(raw[c][j]);
                    const float bb = bf2f(raw[c + 2][j]);
                    o[c][j]     = f2bf(a * cs.x - bb * cs.y);
                    o[c + 2][j] = f2bf(bb * cs.x + a * cs.y);
                }
            #pragma unroll
            for (int c = 0; c < 4; ++c)
                qf[g][c] = *(const bf16x8*)o[c];
        }

        f32x4 ctx[2][8] = {};
        float m2[2][4] = {{-1e30f,-1e30f,-1e30f,-1e30f},
                          {-1e30f,-1e30f,-1e30f,-1e30f}};
        float li[2][4] = {};

        ushort* Kc = lds;
        ushort* Vc = lds + 8192;
        ushort* Fr = lds + 16384;

        stageK(Kc, 0);
        stageV(Vc, 0);
        __syncthreads();

        for (int kt = 0; kt <= qt; ++kt) {
            const int kt0 = kt * 64;

            // ---- QK^T ----
            f32x4 sc2[2][4] = {};
            __builtin_amdgcn_s_setprio(1);
            #pragma unroll
            for (int c = 0; c < 4; ++c)
                #pragma unroll
                for (int nt = 0; nt < 4; ++nt) {
                    const int krow = nt * 16 + colL;
                    const bf16x8 kf = *(const bf16x8*)
                        &Kc[krow * 128 + (((c * 4 + quad) ^ (krow & 15)) << 3)];
                    sc2[0][nt] = __builtin_amdgcn_mfma_f32_16x16x32_bf16(
                        qf[0][c], kf, sc2[0][nt], 0, 0, 0);
                    sc2[1][nt] = __builtin_amdgcn_mfma_f32_16x16x32_bf16(
                        qf[1][c], kf, sc2[1][nt], 0, 0, 0);
                }
            __builtin_amdgcn_s_setprio(0);

            __syncthreads();   // all waves done reading Kc
            if (kt < qt) {
                stageK(Fr, kt0 + 64);
                stageV(Kc, kt0 + 64);
            }

            const bool dmask = (kt == qt);
            // ---- online softmax (exp2 domain, defer-max T13) ----
            #pragma unroll
            for (int g = 0; g < 2; ++g)
                #pragma unroll
                for (int reg = 0; reg < 4; ++reg) {
                    const int row = r0w + g * 16 + quad * 4 + reg;
                    float s[4];
                    #pragma unroll
                    for (int nt = 0; nt < 4; ++nt) {
                        float v = sc2[g][nt][reg] * scale2;
                        if (dmask && (kt0 + nt * 16 + colL > row)) v = -1e9f;
                        s[nt] = v;
                    }
                    float mx = fmaxf(fmaxf(s[0], s[1]), fmaxf(s[2], s[3]));
                    #pragma unroll
                    for (int off = 8; off >= 1; off >>= 1)
                        mx = fmaxf(mx, __shfl_xor(mx, off));
                    if (__any(mx > m2[g][reg] + 11.0f)) {
                        const float mnew  = fmaxf(m2[g][reg], mx);
                        const float alpha = exp2f(m2[g][reg] - mnew);
                        li[g][reg] *= alpha;
                        m2[g][reg] = mnew;
                        #pragma unroll
                        for (int nt2 = 0; nt2 < 8; ++nt2)
                            ctx[g][nt2][reg] *= alpha;
                    }
                    float rs = 0.f;
                    #pragma unroll
                    for (int nt = 0; nt < 4; ++nt) {
                        const float pv = exp2f(s[nt] - m2[g][reg]);
                        s[nt] = pv;
                        rs += pv;
                    }
                    #pragma unroll
                    for (int off = 8; off >= 1; off >>= 1)
                        rs += __shfl_xor(rs, off);
                    li[g][reg] += rs;
                    #pragma unroll
                    for (int nt = 0; nt < 4; ++nt)
                        Pw[(g * 16 + quad * 4 + reg) * 72 + nt * 16 + colL]
                            = f2bf(s[nt]);
                }

            // ---- PV ----
            __builtin_amdgcn_s_setprio(1);
            #pragma unroll
            for (int c2 = 0; c2 < 2; ++c2) {
                const bf16x8 pf0 = *(const bf16x8*)
                    &Pw[colL * 72 + c2 * 32 + quad * 8];
                const bf16x8 pf1 = *(const bf16x8*)
                    &Pw[(16 + colL) * 72 + c2 * 32 + quad * 8];
                #pragma unroll
                for (int nt2 = 0; nt2 < 8; ++nt2) {
                    const int vrow = nt2 * 16 + colL;
                    const bf16x8 vf = *(const bf16x8*)
                        &Vc[vrow * 64 + (((c2 * 4 + quad) ^ (vrow & 7)) << 3)];
                    ctx[0][nt2] = __builtin_amdgcn_mfma_f32_16x16x32_bf16(
                        pf0, vf, ctx[0][nt2], 0, 0, 0);
                    ctx[1][nt2] = __builtin_amdgcn_mfma_f32_16x16x32_bf16(
                        pf1, vf, ctx[1][nt2], 0, 0, 0);
                }
            }
            __builtin_amdgcn_s_setprio(0);

            __syncthreads();
            ushort* tmp = Fr; Fr = Vc; Vc = Kc; Kc = tmp;
        }

        float invl[2][4];
        #pragma unroll
        for (int g = 0; g < 2; ++g)
            #pragma unroll
            for (int reg = 0; reg < 4; ++reg)
                invl[g][reg] = 1.0f / li[g][reg];

        // ---- differential combine through LDS ----
        float* comb = (float*)lds;   // [64][130] f32
        __syncthreads();
        if (p == 1) {
            #pragma unroll
            for (int g = 0; g < 2; ++g)
                #pragma unroll
                for (int nt2 = 0; nt2 < 8; ++nt2)
                    #pragma unroll
                    for (int reg = 0; reg < 4; ++reg)
                        comb[(slot * 32 + g * 16 + quad * 4 + reg) * 130
                             + nt2 * 16 + colL] = ctx[g][nt2][reg] * invl[g][reg];
        }
        __syncthreads();
        if (p == 0) {
            #pragma unroll
            for (int g = 0; g < 2; ++g)
                #pragma unroll
                for (int reg = 0; reg < 4; ++reg) {
                    const int row = r0w + g * 16 + quad * 4 + reg;
                    const float lamv = Lam[(size_t)(b * 2048 + row) * 16 + h];
                    ushort* orow = OutB + (size_t)(b * 2048 + row) * 2048 + h * 128;
                    #pragma unroll
                    for (int nt2 = 0; nt2 < 8; ++nt2) {
                        const float c1 = comb[(slot * 32 + g * 16 + quad * 4 + reg) * 130
                                              + nt2 * 16 + colL];
                        const float o = ctx[g][nt2][reg] * invl[g][reg] - lamv * c1;
                        orow[nt2 * 16 + colL] = f2bf(o);
                    }
                }
        }
        __syncthreads();
    }
}

// ---------------------------------------------------------------------------
extern "C" void kernel_launch(void* const* d_in, const int* in_sizes, int n_in,
                              void* d_out, int out_size, void* d_ws, size_t ws_size,
                              hipStream_t stream)
{
    const float* x  = (const float*)d_in[0];
    const float* Wq = (const float*)d_in[1];
    const float* Wk = (const float*)d_in[2];
    const float* Wv = (const float*)d_in[3];
    const float* Wl = (const float*)d_in[4];
    const float* bl = (const float*)d_in[5];
    const float* Wo = (const float*)d_in[6];
    float* out = (float*)d_out;
    (void)ws_size; (void)in_sizes; (void)n_in; (void)out_size;

    ushort* ws   = (ushort*)d_ws;
    ushort* xb   = ws;                       // 4096x2048
    ushort* Qb16 = xb   + (size_t)8388608;   // 4096x4096
    ushort* Kb16 = Qb16 + (size_t)16777216;  // 4096x2048
    ushort* Vtg  = Kb16 + (size_t)8388608;   // 2x16x128x2048 (V^T)
    ushort* Wqt  = Vtg  + (size_t)8388608;   // 4096x2048 (Wq^T)
    ushort* Wkt  = Wqt  + (size_t)8388608;   // 2048x2048
    ushort* Wvt  = Wkt  + (size_t)4194304;   // 2048x2048
    ushort* Wot  = Wvt  + (size_t)4194304;   // 2048x2048
    ushort* OutB = Wot  + (size_t)4194304;   // 4096x2048
    float*  LamB = (float*)(OutB + (size_t)8388608);  // 4096x16
    float2* Rtab = (float2*)(LamB + (size_t)65536);   // 2048x64

    // dtype conversions + tables
    cvt_bf16<<<4096, 256, 0, stream>>>(x, xb);
    transpose_cvt<<<dim3(128, 64), 256, 0, stream>>>(Wq, Wqt, 2048, 4096);
    transpose_cvt<<<dim3(64, 64), 256, 0, stream>>>(Wk, Wkt, 2048, 2048);
    transpose_cvt<<<dim3(64, 64), 256, 0, stream>>>(Wv, Wvt, 2048, 2048);
    transpose_cvt<<<dim3(64, 64), 256, 0, stream>>>(Wo, Wot, 2048, 2048);
    lam_kernel<<<512, 256, 0, stream>>>(x, Wl, bl, LamB);
    rope_table<<<512, 256, 0, stream>>>(Rtab);

    // projections: Qproj 256x256 tile (grid 256); N=2048 GEMMs 128x256 tile
    // (grid 8x32 = 256 blocks = full machine; R14's 256x256 left half idle)
    gemm_t<1, 8><<<dim3(16, 16), 512, 0, stream>>>(xb, Wqt, Qb16, M_ROWS, 4096, D_MODEL);
    gemm_t<1, 4><<<dim3(8, 32), 512, 0, stream>>>(xb, Wkt, Kb16, M_ROWS, D_MODEL, D_MODEL);
    gemm_t<3, 4><<<dim3(8, 32), 512, 0, stream>>>(xb, Wvt, Vtg, M_ROWS, D_MODEL, D_MODEL);

    // RoPE on K (Q RoPE fused in attention)
    rope_k<<<8192, 256, 0, stream>>>(Kb16, Rtab);

    // MFMA differential causal flash attention -> OutB (bf16)
    attn_mfma<<<dim3(16, NH, 2), 256, 0, stream>>>(Qb16, Kb16, Vtg, LamB, Rtab, OutB);

    // final projection (fp32 out)
    gemm_t<0, 4><<<dim3(8, 32), 512, 0, stream>>>(OutB, Wot, out, M_ROWS, D_MODEL, D_MODEL);
}